// Round 18
// baseline (159.971 us; speedup 1.0000x reference)
//
#include <hip/hip_runtime.h>
#include <hip/hip_bf16.h>

#define IN_F  4096
#define OUT_F 11008
#define SEQ   512
#define NOUT  4096

#define BM 128
#define BN 64
#define BK 128                  // int8 K-tile
#define NT   (IN_F / BK)        // 32 K-phases
#define NBLK (OUT_F / BN)       // 172
#define MBLK (SEQ / BM)         // 4
#define NWG  (NBLK * MBLK)      // 688 = 8 * 86 -> bijective XCD swizzle

#define HSLOTS 8192             // dedup hash table (load factor 0.5)

// prep_all grid layout: block 0 = dedup+table; 1..512 = X quant rows;
// 513..11520 = Q pack chunks (4096 int32 each).
#define PREP_XQ_BASE 1
#define PREP_Q8_BASE (PREP_XQ_BASE + SEQ)
#define PREP_NWG     (PREP_Q8_BASE + (OUT_F * IN_F / 4096))

// ws layout: Xq int8 (2MB) | xscale | tabi | tabf | hkey | hval | Qb8 (45MB)
#define WS_XSC   ((size_t)SEQ * IN_F)
#define WS_TAB_I (WS_XSC + (size_t)SEQ * 4)
#define WS_TAB_F (WS_TAB_I + (size_t)NOUT * 4)
#define WS_HKEY  (WS_TAB_F + (size_t)NOUT * 4)
#define WS_HVAL  (WS_HKEY + (size_t)HSLOTS * 4)
#define WS_QB8   (WS_HVAL + (size_t)HSLOTS * 4)
#define WS_NEED  (WS_QB8 + (size_t)OUT_F * IN_F)

typedef __attribute__((ext_vector_type(4))) float f32x4;
typedef __attribute__((ext_vector_type(4))) int   int4v;
typedef __attribute__((ext_vector_type(4))) float float4v;

__device__ __forceinline__ unsigned hslot(int key) {
    return ((unsigned)key * 2654435761u) & (HSLOTS - 1);
}

__device__ __forceinline__ int pack4(int a, int b, int c, int d) {
    return (a & 255) | ((b & 255) << 8) | ((c & 255) << 16) | (d << 24);
}

// ---- single prep kernel: all pre-GEMM work in ONE launch ----
// block 0: outlier dedup (init+insert+resolve, intra-block barriers,
//          global-atomic hash) + delta table.  [~8us, hidden under q8]
// blocks 1..512: per-row absmax int8 quantization of X (R11-proven).
// blocks 513..11520: Q int32 -> packed int8 (16 int32 -> 16B per thread).
__global__ __launch_bounds__(256) void prep_all(
    const float* __restrict__ X,
    const int*   __restrict__ Q,
    const float* __restrict__ scale,
    const float* __restrict__ outv,
    const int*   __restrict__ oidx,
    char*  __restrict__ Xq,
    float* __restrict__ xsc,
    char*  __restrict__ Qb8,
    int*   __restrict__ tabi,
    float* __restrict__ tabf,
    int*   __restrict__ hkey,
    int*   __restrict__ hval,
    int do_q8)
{
    const int b   = blockIdx.x;
    const int tid = threadIdx.x;

    if (b == 0) {
        // --- dedup: init, insert (last-wins via atomicMax), resolve ---
        for (int i = tid; i < HSLOTS; i += 256) { hkey[i] = -1; hval[i] = -1; }
        __syncthreads();
        for (int j = tid; j < NOUT; j += 256) {
            const int key = oidx[2 * j] * IN_F + oidx[2 * j + 1];
            unsigned s = hslot(key);
            while (true) {
                const int prev = atomicCAS(&hkey[s], -1, key);
                if (prev == -1 || prev == key) break;
                s = (s + 1) & (HSLOTS - 1);
            }
            atomicMax(&hval[s], j);
        }
        __syncthreads();
        for (int j = tid; j < NOUT; j += 256) {
            const int r = oidx[2 * j], c = oidx[2 * j + 1];
            const int key = r * IN_F + c;
            unsigned s = hslot(key);
            while (hkey[s] != key) s = (s + 1) & (HSLOTS - 1);
            if (hval[s] != j) { tabi[j] = -1; tabf[j] = 0.f; continue; }
            tabi[j] = (r << 16) | c;
            tabf[j] = outv[j] - (float)Q[(size_t)r * IN_F + c] * scale[r];
        }
        return;
    }

    if (b < PREP_Q8_BASE) {
        // --- X quant: one block per row ---
        const int row = b - PREP_XQ_BASE;
        const float* src = X + (size_t)row * IN_F + tid * 16;
        float4v x0 = *(const float4v*)(src + 0);
        float4v x1 = *(const float4v*)(src + 4);
        float4v x2 = *(const float4v*)(src + 8);
        float4v x3 = *(const float4v*)(src + 12);

        float m = 0.f;
        #pragma unroll
        for (int j = 0; j < 4; ++j) {
            m = fmaxf(m, fabsf(x0[j])); m = fmaxf(m, fabsf(x1[j]));
            m = fmaxf(m, fabsf(x2[j])); m = fmaxf(m, fabsf(x3[j]));
        }
        #pragma unroll
        for (int off = 32; off > 0; off >>= 1)
            m = fmaxf(m, __shfl_xor(m, off));
        __shared__ float wmax[4];
        if ((tid & 63) == 0) wmax[tid >> 6] = m;
        __syncthreads();
        const float amax = fmaxf(fmaxf(wmax[0], wmax[1]), fmaxf(wmax[2], wmax[3]));
        const float inv = (amax > 0.f) ? (127.f / amax) : 0.f;

        int4v o;
        o[0] = pack4(__float2int_rn(x0[0]*inv), __float2int_rn(x0[1]*inv),
                     __float2int_rn(x0[2]*inv), __float2int_rn(x0[3]*inv));
        o[1] = pack4(__float2int_rn(x1[0]*inv), __float2int_rn(x1[1]*inv),
                     __float2int_rn(x1[2]*inv), __float2int_rn(x1[3]*inv));
        o[2] = pack4(__float2int_rn(x2[0]*inv), __float2int_rn(x2[1]*inv),
                     __float2int_rn(x2[2]*inv), __float2int_rn(x2[3]*inv));
        o[3] = pack4(__float2int_rn(x3[0]*inv), __float2int_rn(x3[1]*inv),
                     __float2int_rn(x3[2]*inv), __float2int_rn(x3[3]*inv));
        *(int4v*)(Xq + (size_t)row * IN_F + tid * 16) = o;
        if (tid == 0) xsc[row] = (amax > 0.f) ? (amax / 127.f) : 0.f;
        return;
    }

    if (do_q8) {
        // --- Q pack: 16 int32 -> 16B per thread ---
        const size_t i = ((size_t)(b - PREP_Q8_BASE) * 256 + tid) * 16;
        int4v q0 = *(const int4v*)(Q + i);
        int4v q1 = *(const int4v*)(Q + i + 4);
        int4v q2 = *(const int4v*)(Q + i + 8);
        int4v q3 = *(const int4v*)(Q + i + 12);
        int4v o;
        o[0] = pack4(q0[0], q0[1], q0[2], q0[3]);
        o[1] = pack4(q1[0], q1[1], q1[2], q1[3]);
        o[2] = pack4(q2[0], q2[1], q2[2], q2[3]);
        o[3] = pack4(q3[0], q3[1], q3[2], q3[3]);
        *(int4v*)(Qb8 + i) = o;
    }
}

// ---- main: R16's qgemm15 VERBATIM (best measured: 110.4us total).
// 128x64x128 int8 lean loop @ 512 threads / 8 waves: 96KB ingress per wave,
// grid 688 = single balanced residency round (3 blocks/CU). Zero in-loop
// VALU; both operands via global_load_lds (src XOR-preswizzled);
// acc[2][2]=16 VGPR; compile-time epilogue indices (rule-#20 safe).
__global__ __launch_bounds__(512, 6) void qgemm15(
    const char*  __restrict__ Xq,
    const float* __restrict__ xsc,
    const float* __restrict__ X,
    const char*  __restrict__ Qb8,
    const float* __restrict__ scale,
    const float* __restrict__ bias,
    const int*   __restrict__ tabi,
    const float* __restrict__ tabf,
    float* __restrict__ out)
{
    __shared__ char sA[2][BM * BK];   // 32 KB
    __shared__ char sB[2][BN * BK];   // 16 KB
    __shared__ int   list[256];
    __shared__ float ldel[256];
    __shared__ int   lcount;

    const int tid  = threadIdx.x;
    const int wave = tid >> 6;         // 0..7
    const int lane = tid & 63;

    // XCD swizzle; 4 consecutive tiles share one Qb8 panel (L2 reuse).
    const int lin = blockIdx.x;
    const int t0  = (lin & 7) * (NWG / 8) + (lin >> 3);
    const int col0 = (t0 >> 2) * BN;
    const int row0 = (t0 & 3) * BM;

    const int wm = (wave >> 1) * 32;   // wave out sub-tile: 32x32 (4x2 grid)
    const int wn = (wave & 1) * 32;
    const int fr = lane & 15;          // fragment row within 16
    const int fc = lane >> 4;          // k-chunk group 0..3 (16B chunks)

    int4v acc[2][2] = {};              // 16 VGPR i32 accumulator

    // Staging: per tile A 16KB (2 instr/wave) + B 8KB (1 instr/wave).
    // Each gload_lds writes 1KB linear: lane l -> row base+(l>>3), slot l&7.
    // Source chunk XOR-preswizzled (m173): LDS slot s of row r = logical s^(r&7).
    const char* asrc =
        Xq + (size_t)(row0 + wave * 16 + (lane >> 3)) * IN_F
           + (((lane & 7) ^ (lane >> 3)) * 16);
    const char* bsrc =
        Qb8 + (size_t)(col0 + wave * 8 + (lane >> 3)) * IN_F
            + (((lane & 7) ^ (lane >> 3)) * 16);

    auto issueAB = [&](int buf, int k0) {   // 3 gload_lds per thread
        #pragma unroll
        for (int i = 0; i < 2; ++i)
            __builtin_amdgcn_global_load_lds(
                (const __attribute__((address_space(1))) void*)(asrc + (size_t)i * 8 * IN_F + k0),
                (__attribute__((address_space(3))) void*)&sA[buf][(wave * 16 + i * 8) * BK],
                16, 0, 0);
        __builtin_amdgcn_global_load_lds(
            (const __attribute__((address_space(1))) void*)(bsrc + k0),
            (__attribute__((address_space(3))) void*)&sB[buf][(wave * 8) * BK],
            16, 0, 0);
    };

    // Prologue.
    issueAB(0, 0);
    asm volatile("s_waitcnt vmcnt(0) lgkmcnt(0)" ::: "memory");
    __builtin_amdgcn_s_barrier();

    for (int t = 0; t < NT; ++t) {
        const int cur = t & 1;
        if (t + 1 < NT) issueAB(cur ^ 1, (t + 1) * BK);   // prefetch t+1

        __builtin_amdgcn_s_setprio(1);
        #pragma unroll
        for (int kk = 0; kk < 2; ++kk) {
            int4v fa[2], fb[2];
            #pragma unroll
            for (int mi = 0; mi < 2; ++mi) {
                const int row = wm + mi * 16 + fr;
                fa[mi] = *(const int4v*)&sA[cur][row * BK + (((kk * 4 + fc) ^ (row & 7)) * 16)];
            }
            #pragma unroll
            for (int ni = 0; ni < 2; ++ni) {
                const int row = wn + ni * 16 + fr;
                fb[ni] = *(const int4v*)&sB[cur][row * BK + (((kk * 4 + fc) ^ (row & 7)) * 16)];
            }
            #pragma unroll
            for (int mi = 0; mi < 2; ++mi)
                #pragma unroll
                for (int ni = 0; ni < 2; ++ni)
                    acc[mi][ni] = __builtin_amdgcn_mfma_i32_16x16x64_i8(
                        fa[mi], fb[ni], acc[mi][ni], 0, 0, 0);
        }
        __builtin_amdgcn_s_setprio(0);

        asm volatile("s_waitcnt vmcnt(0) lgkmcnt(0)" ::: "memory");
        __builtin_amdgcn_s_barrier();
    }

    // Scales: out = xscale[row] * qscale[col] * acc (exact i32 sum).
    const int ec = fr;
    const int er = fc * 4;
    f32x4 facc[2][2];
    #pragma unroll
    for (int ni = 0; ni < 2; ++ni) {
        const float qsc = scale[col0 + wn + ni * 16 + ec];
        #pragma unroll
        for (int mi = 0; mi < 2; ++mi) {
            #pragma unroll
            for (int r = 0; r < 4; ++r) {
                const float xs = xsc[row0 + wm + mi * 16 + er + r];
                facc[mi][ni][r] = (float)acc[mi][ni][r] * qsc * xs;
            }
        }
    }

    // Outlier deltas -> registers (compile-time nn via unroll+predicate).
    if (tid == 0) lcount = 0;
    __syncthreads();
    for (int c = tid; c < NOUT; c += 512) {
        const int p = tabi[c];
        const int r = p >> 16;
        if (r >= col0 && r < col0 + BN) {
            const int pos = atomicAdd(&lcount, 1);
            if (pos < 256) { list[pos] = p; ldel[pos] = tabf[c]; }
        }
    }
    __syncthreads();
    const int nm = lcount < 256 ? lcount : 256;
    for (int u = 0; u < nm; ++u) {
        const int p    = list[u];
        const int ocl  = (p >> 16) - col0;   // 0..63
        const int ocol = p & 0xFFFF;
        if (((ocl >> 5) == (wave & 1)) && ((lane & 15) == (ocl & 15))) {
            const float d = ldel[u];
            #pragma unroll
            for (int nn = 0; nn < 2; ++nn) {
                if (nn == ((ocl >> 4) & 1)) {
                    #pragma unroll
                    for (int mi = 0; mi < 2; ++mi)
                        #pragma unroll
                        for (int r2 = 0; r2 < 4; ++r2) {
                            const int grow = row0 + wm + mi * 16 + er + r2;
                            facc[mi][nn][r2] += d * X[(size_t)grow * IN_F + ocol];
                        }
                }
            }
        }
    }

    // Bias + store. C/D: col=lane&15, row=(lane>>4)*4+reg (dtype-independent).
    #pragma unroll
    for (int ni = 0; ni < 2; ++ni) {
        const int gcol = col0 + wn + ni * 16 + ec;
        const float bv = bias[gcol];
        #pragma unroll
        for (int mi = 0; mi < 2; ++mi) {
            const int grow = row0 + wm + mi * 16 + er;
            #pragma unroll
            for (int r = 0; r < 4; ++r)
                out[(size_t)(grow + r) * OUT_F + gcol] = facc[mi][ni][r] + bv;
        }
    }
}

// ---- fallback (small ws; never expected — ws proven ~721MB): R11-style
// direct-Q kernel (BM=128, BN=64, BK=128, grid 688), Q int32 reg-staged.
__global__ __launch_bounds__(256) void qgemm10_fb(
    const char*  __restrict__ Xq,
    const float* __restrict__ xsc,
    const float* __restrict__ X,
    const int*   __restrict__ Q,
    const float* __restrict__ scale,
    const float* __restrict__ bias,
    const int*   __restrict__ tabi,
    const float* __restrict__ tabf,
    float* __restrict__ out)
{
    __shared__ char sA[2][BM * BK];
    __shared__ char sB[2][BN * BK];
    __shared__ int   list[256];
    __shared__ float ldel[256];
    __shared__ int   lcount;

    const int tid  = threadIdx.x;
    const int wave = tid >> 6;
    const int lane = tid & 63;

    const int lin = blockIdx.x;
    const int t0  = (lin & 7) * (NWG / 8) + (lin >> 3);
    const int col0 = (t0 >> 2) * BN;
    const int row0 = (t0 & 3) * BM;

    const int wm = (wave >> 1) * 64;
    const int wn = (wave & 1) * 32;
    const int fr = lane & 15;
    const int fc = lane >> 4;

    int4v acc[4][2] = {};

    const char* asrc =
        Xq + (size_t)(row0 + wave * 32 + (lane >> 3)) * IN_F
           + (((lane & 7) ^ (lane >> 3)) * 16);
    auto issueA = [&](int buf, int k0) {
        #pragma unroll
        for (int i = 0; i < 4; ++i)
            __builtin_amdgcn_global_load_lds(
                (const __attribute__((address_space(1))) void*)(asrc + (size_t)i * 8 * IN_F + k0),
                (__attribute__((address_space(3))) void*)&sA[buf][(wave * 32 + i * 8) * BK],
                16, 0, 0);
    };

    const int srb = tid >> 2;
    const int* bsrc = Q + (size_t)(col0 + srb) * IN_F + (tid & 3) * 32;
    int4v br0, br1, br2, br3, br4, br5, br6, br7;
    auto loadB = [&](int k0) {
        br0 = *(const int4v*)(bsrc + k0 + 0);
        br1 = *(const int4v*)(bsrc + k0 + 4);
        br2 = *(const int4v*)(bsrc + k0 + 8);
        br3 = *(const int4v*)(bsrc + k0 + 12);
        br4 = *(const int4v*)(bsrc + k0 + 16);
        br5 = *(const int4v*)(bsrc + k0 + 20);
        br6 = *(const int4v*)(bsrc + k0 + 24);
        br7 = *(const int4v*)(bsrc + k0 + 28);
    };
    auto writeB = [&](int buf) {
        int4v w0, w1;
        w0[0] = pack4(br0[0], br0[1], br0[2], br0[3]);
        w0[1] = pack4(br1[0], br1[1], br1[2], br1[3]);
        w0[2] = pack4(br2[0], br2[1], br2[2], br2[3]);
        w0[3] = pack4(br3[0], br3[1], br3[2], br3[3]);
        w1[0] = pack4(br4[0], br4[1], br4[2], br4[3]);
        w1[1] = pack4(br5[0], br5[1], br5[2], br5[3]);
        w1[2] = pack4(br6[0], br6[1], br6[2], br6[3]);
        w1[3] = pack4(br7[0], br7[1], br7[2], br7[3]);
        const int c0 = (tid & 3) * 2;
        const int s7 = srb & 7;
        *(int4v*)&sB[buf][srb * BK + ((c0 ^ s7) * 16)]       = w0;
        *(int4v*)&sB[buf][srb * BK + (((c0 + 1) ^ s7) * 16)] = w1;
    };

    loadB(0);
    issueA(0, 0);
    writeB(0);
    loadB(BK);
    asm volatile("s_waitcnt vmcnt(8) lgkmcnt(0)" ::: "memory");
    __builtin_amdgcn_s_barrier();

    for (int t = 0; t < NT; ++t) {
        const int cur = t & 1;
        if (t + 1 < NT) issueA(cur ^ 1, (t + 1) * BK);

        __builtin_amdgcn_s_setprio(1);
        #pragma unroll
        for (int kk = 0; kk < 2; ++kk) {
            int4v fa[4], fb[2];
            #pragma unroll
            for (int mi = 0; mi < 4; ++mi) {
                const int row = wm + mi * 16 + fr;
                fa[mi] = *(const int4v*)&sA[cur][row * BK + (((kk * 4 + fc) ^ (row & 7)) * 16)];
            }
            #pragma unroll
            for (int ni = 0; ni < 2; ++ni) {
                const int row = wn + ni * 16 + fr;
                fb[ni] = *(const int4v*)&sB[cur][row * BK + (((kk * 4 + fc) ^ (row & 7)) * 16)];
            }
            #pragma unroll
            for (int mi = 0; mi < 4; ++mi)
                #pragma unroll
                for (int ni = 0; ni < 2; ++ni)
                    acc[mi][ni] = __builtin_amdgcn_mfma_i32_16x16x64_i8(
                        fa[mi], fb[ni], acc[mi][ni], 0, 0, 0);
        }
        __builtin_amdgcn_s_setprio(0);

        if (t + 1 < NT) writeB(cur ^ 1);
        if (t + 2 < NT) loadB((t + 2) * BK);

        if (t + 2 < NT)
            asm volatile("s_waitcnt vmcnt(8) lgkmcnt(0)" ::: "memory");
        else
            asm volatile("s_waitcnt vmcnt(0) lgkmcnt(0)" ::: "memory");
        __builtin_amdgcn_s_barrier();
    }

    const int ec = fr;
    const int er = fc * 4;
    float xs_[4][4];
    #pragma unroll
    for (int mi = 0; mi < 4; ++mi)
        #pragma unroll
        for (int r = 0; r < 4; ++r)
            xs_[mi][r] = xsc[row0 + wm + mi * 16 + er + r];

    f32x4 facc[4][2];
    #pragma unroll
    for (int ni = 0; ni < 2; ++ni) {
        const float qsc = scale[col0 + wn + ni * 16 + ec];
        #pragma unroll
        for (int mi = 0; mi < 4; ++mi)
            #pragma unroll
            for (int r = 0; r < 4; ++r)
                facc[mi][ni][r] = (float)acc[mi][ni][r] * qsc * xs_[mi][r];
    }

    if (tid == 0) lcount = 0;
    __syncthreads();
    for (int c = tid; c < NOUT; c += 256) {
        const int p = tabi[c];
        const int r = p >> 16;
        if (r >= col0 && r < col0 + BN) {
            const int pos = atomicAdd(&lcount, 1);
            if (pos < 256) { list[pos] = p; ldel[pos] = tabf[c]; }
        }
    }
    __syncthreads();
    const int nm = lcount < 256 ? lcount : 256;
    for (int u = 0; u < nm; ++u) {
        const int p    = list[u];
        const int ocl  = (p >> 16) - col0;
        const int ocol = p & 0xFFFF;
        if (((ocl >> 5) == (wave & 1)) && ((lane & 15) == (ocl & 15))) {
            const float d = ldel[u];
            #pragma unroll
            for (int nn = 0; nn < 2; ++nn) {
                if (nn == ((ocl >> 4) & 1)) {
                    #pragma unroll
                    for (int mi = 0; mi < 4; ++mi)
                        #pragma unroll
                        for (int r2 = 0; r2 < 4; ++r2) {
                            const int grow = row0 + wm + mi * 16 + er + r2;
                            facc[mi][nn][r2] += d * X[(size_t)grow * IN_F + ocol];
                        }
                }
            }
        }
    }

    #pragma unroll
    for (int ni = 0; ni < 2; ++ni) {
        const int gcol = col0 + wn + ni * 16 + ec;
        const float bv = bias[gcol];
        #pragma unroll
        for (int mi = 0; mi < 4; ++mi) {
            const int grow = row0 + wm + mi * 16 + er;
            #pragma unroll
            for (int r = 0; r < 4; ++r)
                out[(size_t)(grow + r) * OUT_F + gcol] = facc[mi][ni][r] + bv;
        }
    }
}

extern "C" void kernel_launch(void* const* d_in, const int* in_sizes, int n_in,
                              void* d_out, int out_size, void* d_ws, size_t ws_size,
                              hipStream_t stream) {
    const float* x    = (const float*)d_in[0];
    const int*   q    = (const int*)d_in[1];
    const float* qs   = (const float*)d_in[2];
    const float* qo   = (const float*)d_in[3];
    const int*   qi   = (const int*)d_in[4];
    const float* bias = (const float*)d_in[5];
    float* out = (float*)d_out;

    char*  Xq   = (char*)d_ws;
    float* xsc  = (float*)((char*)d_ws + WS_XSC);
    int*   tabi = (int*)((char*)d_ws + WS_TAB_I);
    float* tabf = (float*)((char*)d_ws + WS_TAB_F);
    int*   hkey = (int*)((char*)d_ws + WS_HKEY);
    int*   hval = (int*)((char*)d_ws + WS_HVAL);
    char*  Qb8  = (char*)d_ws + WS_QB8;

    if (ws_size >= WS_NEED) {
        prep_all<<<dim3(PREP_NWG), 256, 0, stream>>>(
            x, q, qs, qo, qi, Xq, xsc, Qb8, tabi, tabf, hkey, hval, 1);
        qgemm15<<<dim3(NWG), 512, 0, stream>>>(Xq, xsc, x, Qb8, qs, bias, tabi, tabf, out);
    } else {
        prep_all<<<dim3(PREP_Q8_BASE), 256, 0, stream>>>(
            x, q, qs, qo, qi, Xq, xsc, Qb8, tabi, tabf, hkey, hval, 0);
        qgemm10_fb<<<dim3(NWG), 256, 0, stream>>>(Xq, xsc, x, q, qs, bias, tabi, tabf, out);
    }
}

// Round 19
// 110.281 us; speedup vs baseline: 1.4506x; 1.4506x over previous
//
#include <hip/hip_runtime.h>
#include <hip/hip_bf16.h>

#define IN_F  4096
#define OUT_F 11008
#define SEQ   512
#define NOUT  4096

#define BM 128
#define BN 64
#define BK 128                  // int8 K-tile
#define NT   (IN_F / BK)        // 32 K-phases
#define NBLK (OUT_F / BN)       // 172
#define MBLK (SEQ / BM)         // 4
#define NWG  (NBLK * MBLK)      // 688 = 8 * 86 -> bijective XCD swizzle

#define HSLOTS 8192             // dedup hash table (load factor 0.5)

// ws layout: Xq int8 (2MB) | xscale | tabi | tabf | hkey | hval | Qb8 (45MB)
#define WS_XSC   ((size_t)SEQ * IN_F)
#define WS_TAB_I (WS_XSC + (size_t)SEQ * 4)
#define WS_TAB_F (WS_TAB_I + (size_t)NOUT * 4)
#define WS_HKEY  (WS_TAB_F + (size_t)NOUT * 4)
#define WS_HVAL  (WS_HKEY + (size_t)HSLOTS * 4)
#define WS_QB8   (WS_HVAL + (size_t)HSLOTS * 4)
#define WS_NEED  (WS_QB8 + (size_t)OUT_F * IN_F)

typedef __attribute__((ext_vector_type(4))) float f32x4;
typedef __attribute__((ext_vector_type(4))) int   int4v;
typedef __attribute__((ext_vector_type(4))) float float4v;

__device__ __forceinline__ unsigned hslot(int key) {
    return ((unsigned)key * 2654435761u) & (HSLOTS - 1);
}

__device__ __forceinline__ int pack4(int a, int b, int c, int d) {
    return (a & 255) | ((b & 255) << 8) | ((c & 255) << 16) | (d << 24);
}

// ---- prep 1: per-row absmax int8 quantization of X (R11-proven) ----
__global__ __launch_bounds__(256) void prep_xq(const float* __restrict__ X,
                                               char* __restrict__ Xq,
                                               float* __restrict__ xsc) {
    const int row = blockIdx.x;
    const int tid = threadIdx.x;
    const float* src = X + (size_t)row * IN_F + tid * 16;
    float4v x0 = *(const float4v*)(src + 0);
    float4v x1 = *(const float4v*)(src + 4);
    float4v x2 = *(const float4v*)(src + 8);
    float4v x3 = *(const float4v*)(src + 12);

    float m = 0.f;
    #pragma unroll
    for (int j = 0; j < 4; ++j) {
        m = fmaxf(m, fabsf(x0[j])); m = fmaxf(m, fabsf(x1[j]));
        m = fmaxf(m, fabsf(x2[j])); m = fmaxf(m, fabsf(x3[j]));
    }
    #pragma unroll
    for (int off = 32; off > 0; off >>= 1)
        m = fmaxf(m, __shfl_xor(m, off));
    __shared__ float wmax[4];
    if ((tid & 63) == 0) wmax[tid >> 6] = m;
    __syncthreads();
    const float amax = fmaxf(fmaxf(wmax[0], wmax[1]), fmaxf(wmax[2], wmax[3]));
    const float inv = (amax > 0.f) ? (127.f / amax) : 0.f;

    int4v o;
    o[0] = pack4(__float2int_rn(x0[0]*inv), __float2int_rn(x0[1]*inv),
                 __float2int_rn(x0[2]*inv), __float2int_rn(x0[3]*inv));
    o[1] = pack4(__float2int_rn(x1[0]*inv), __float2int_rn(x1[1]*inv),
                 __float2int_rn(x1[2]*inv), __float2int_rn(x1[3]*inv));
    o[2] = pack4(__float2int_rn(x2[0]*inv), __float2int_rn(x2[1]*inv),
                 __float2int_rn(x2[2]*inv), __float2int_rn(x2[3]*inv));
    o[3] = pack4(__float2int_rn(x3[0]*inv), __float2int_rn(x3[1]*inv),
                 __float2int_rn(x3[2]*inv), __float2int_rn(x3[3]*inv));
    *(int4v*)(Xq + (size_t)row * IN_F + tid * 16) = o;
    if (tid == 0) xsc[row] = (amax > 0.f) ? (amax / 127.f) : 0.f;
}

// ---- prep 1b: Q int32 -> packed int8 (thread: 16 int32 -> 16B) ----
__global__ __launch_bounds__(256) void prep_q8(const int* __restrict__ Q,
                                               char* __restrict__ Qb8) {
    const size_t i = ((size_t)blockIdx.x * 256 + threadIdx.x) * 16;
    int4v q0 = *(const int4v*)(Q + i);
    int4v q1 = *(const int4v*)(Q + i + 4);
    int4v q2 = *(const int4v*)(Q + i + 8);
    int4v q3 = *(const int4v*)(Q + i + 12);
    int4v o;
    o[0] = pack4(q0[0], q0[1], q0[2], q0[3]);
    o[1] = pack4(q1[0], q1[1], q1[2], q1[3]);
    o[2] = pack4(q2[0], q2[1], q2[2], q2[3]);
    o[3] = pack4(q3[0], q3[1], q3[2], q3[3]);
    *(int4v*)(Qb8 + i) = o;
}

// ---- prep 2a: insert outliers, last-wins via atomicMax on entry index ----
__global__ __launch_bounds__(256) void prep_hins(const int* __restrict__ oidx,
                                                 int* __restrict__ hkey,
                                                 int* __restrict__ hval) {
    const int j = blockIdx.x * 256 + threadIdx.x;
    const int key = oidx[2 * j] * IN_F + oidx[2 * j + 1];
    unsigned s = hslot(key);
    while (true) {
        const int prev = atomicCAS(&hkey[s], -1, key);
        if (prev == -1 || prev == key) break;
        s = (s + 1) & (HSLOTS - 1);
    }
    atomicMax(&hval[s], j);
}

// ---- prep 2b: resolve dups + delta table (delta vs EXACT q*scale) ----
__global__ __launch_bounds__(256) void prep_tab(
    const int* __restrict__ oidx, const float* __restrict__ outv,
    const int* __restrict__ Q, const float* __restrict__ scale,
    const int* __restrict__ hkey, const int* __restrict__ hval,
    int* __restrict__ tabi, float* __restrict__ tabf) {
    const int j = blockIdx.x * 256 + threadIdx.x;
    const int r = oidx[2 * j], c = oidx[2 * j + 1];
    const int key = r * IN_F + c;
    unsigned s = hslot(key);
    while (hkey[s] != key) s = (s + 1) & (HSLOTS - 1);
    if (hval[s] != j) { tabi[j] = -1; tabf[j] = 0.f; return; }   // later dup wins
    tabi[j] = (r << 16) | c;
    tabf[j] = outv[j] - (float)Q[(size_t)r * IN_F + c] * scale[r];
}

// ---- main: R16's qgemm15 VERBATIM (best measured: 110.4us total).
// 128x64x128 int8 lean loop @ 512 threads / 8 waves: 96KB ingress per wave,
// grid 688 = single balanced residency round (3 blocks/CU). Zero in-loop
// VALU; both operands via global_load_lds (src XOR-preswizzled);
// acc[2][2]=16 VGPR; compile-time epilogue indices (rule-#20 safe).
__global__ __launch_bounds__(512, 6) void qgemm15(
    const char*  __restrict__ Xq,
    const float* __restrict__ xsc,
    const float* __restrict__ X,
    const char*  __restrict__ Qb8,
    const float* __restrict__ scale,
    const float* __restrict__ bias,
    const int*   __restrict__ tabi,
    const float* __restrict__ tabf,
    float* __restrict__ out)
{
    __shared__ char sA[2][BM * BK];   // 32 KB
    __shared__ char sB[2][BN * BK];   // 16 KB
    __shared__ int   list[256];
    __shared__ float ldel[256];
    __shared__ int   lcount;

    const int tid  = threadIdx.x;
    const int wave = tid >> 6;         // 0..7
    const int lane = tid & 63;

    // XCD swizzle; 4 consecutive tiles share one Qb8 panel (L2 reuse).
    const int lin = blockIdx.x;
    const int t0  = (lin & 7) * (NWG / 8) + (lin >> 3);
    const int col0 = (t0 >> 2) * BN;
    const int row0 = (t0 & 3) * BM;

    const int wm = (wave >> 1) * 32;   // wave out sub-tile: 32x32 (4x2 grid)
    const int wn = (wave & 1) * 32;
    const int fr = lane & 15;          // fragment row within 16
    const int fc = lane >> 4;          // k-chunk group 0..3 (16B chunks)

    int4v acc[2][2] = {};              // 16 VGPR i32 accumulator

    // Staging: per tile A 16KB (2 instr/wave) + B 8KB (1 instr/wave).
    // Each gload_lds writes 1KB linear: lane l -> row base+(l>>3), slot l&7.
    // Source chunk XOR-preswizzled (m173): LDS slot s of row r = logical s^(r&7).
    const char* asrc =
        Xq + (size_t)(row0 + wave * 16 + (lane >> 3)) * IN_F
           + (((lane & 7) ^ (lane >> 3)) * 16);
    const char* bsrc =
        Qb8 + (size_t)(col0 + wave * 8 + (lane >> 3)) * IN_F
            + (((lane & 7) ^ (lane >> 3)) * 16);

    auto issueAB = [&](int buf, int k0) {   // 3 gload_lds per thread
        #pragma unroll
        for (int i = 0; i < 2; ++i)
            __builtin_amdgcn_global_load_lds(
                (const __attribute__((address_space(1))) void*)(asrc + (size_t)i * 8 * IN_F + k0),
                (__attribute__((address_space(3))) void*)&sA[buf][(wave * 16 + i * 8) * BK],
                16, 0, 0);
        __builtin_amdgcn_global_load_lds(
            (const __attribute__((address_space(1))) void*)(bsrc + k0),
            (__attribute__((address_space(3))) void*)&sB[buf][(wave * 8) * BK],
            16, 0, 0);
    };

    // Prologue.
    issueAB(0, 0);
    asm volatile("s_waitcnt vmcnt(0) lgkmcnt(0)" ::: "memory");
    __builtin_amdgcn_s_barrier();

    for (int t = 0; t < NT; ++t) {
        const int cur = t & 1;
        if (t + 1 < NT) issueAB(cur ^ 1, (t + 1) * BK);   // prefetch t+1

        __builtin_amdgcn_s_setprio(1);
        #pragma unroll
        for (int kk = 0; kk < 2; ++kk) {
            int4v fa[2], fb[2];
            #pragma unroll
            for (int mi = 0; mi < 2; ++mi) {
                const int row = wm + mi * 16 + fr;
                fa[mi] = *(const int4v*)&sA[cur][row * BK + (((kk * 4 + fc) ^ (row & 7)) * 16)];
            }
            #pragma unroll
            for (int ni = 0; ni < 2; ++ni) {
                const int row = wn + ni * 16 + fr;
                fb[ni] = *(const int4v*)&sB[cur][row * BK + (((kk * 4 + fc) ^ (row & 7)) * 16)];
            }
            #pragma unroll
            for (int mi = 0; mi < 2; ++mi)
                #pragma unroll
                for (int ni = 0; ni < 2; ++ni)
                    acc[mi][ni] = __builtin_amdgcn_mfma_i32_16x16x64_i8(
                        fa[mi], fb[ni], acc[mi][ni], 0, 0, 0);
        }
        __builtin_amdgcn_s_setprio(0);

        asm volatile("s_waitcnt vmcnt(0) lgkmcnt(0)" ::: "memory");
        __builtin_amdgcn_s_barrier();
    }

    // Scales: out = xscale[row] * qscale[col] * acc (exact i32 sum).
    const int ec = fr;
    const int er = fc * 4;
    f32x4 facc[2][2];
    #pragma unroll
    for (int ni = 0; ni < 2; ++ni) {
        const float qsc = scale[col0 + wn + ni * 16 + ec];
        #pragma unroll
        for (int mi = 0; mi < 2; ++mi) {
            #pragma unroll
            for (int r = 0; r < 4; ++r) {
                const float xs = xsc[row0 + wm + mi * 16 + er + r];
                facc[mi][ni][r] = (float)acc[mi][ni][r] * qsc * xs;
            }
        }
    }

    // Outlier deltas -> registers (compile-time nn via unroll+predicate).
    if (tid == 0) lcount = 0;
    __syncthreads();
    for (int c = tid; c < NOUT; c += 512) {
        const int p = tabi[c];
        const int r = p >> 16;
        if (r >= col0 && r < col0 + BN) {
            const int pos = atomicAdd(&lcount, 1);
            if (pos < 256) { list[pos] = p; ldel[pos] = tabf[c]; }
        }
    }
    __syncthreads();
    const int nm = lcount < 256 ? lcount : 256;
    for (int u = 0; u < nm; ++u) {
        const int p    = list[u];
        const int ocl  = (p >> 16) - col0;   // 0..63
        const int ocol = p & 0xFFFF;
        if (((ocl >> 5) == (wave & 1)) && ((lane & 15) == (ocl & 15))) {
            const float d = ldel[u];
            #pragma unroll
            for (int nn = 0; nn < 2; ++nn) {
                if (nn == ((ocl >> 4) & 1)) {
                    #pragma unroll
                    for (int mi = 0; mi < 2; ++mi)
                        #pragma unroll
                        for (int r2 = 0; r2 < 4; ++r2) {
                            const int grow = row0 + wm + mi * 16 + er + r2;
                            facc[mi][nn][r2] += d * X[(size_t)grow * IN_F + ocol];
                        }
                }
            }
        }
    }

    // Bias + store. C/D: col=lane&15, row=(lane>>4)*4+reg (dtype-independent).
    #pragma unroll
    for (int ni = 0; ni < 2; ++ni) {
        const int gcol = col0 + wn + ni * 16 + ec;
        const float bv = bias[gcol];
        #pragma unroll
        for (int mi = 0; mi < 2; ++mi) {
            const int grow = row0 + wm + mi * 16 + er;
            #pragma unroll
            for (int r = 0; r < 4; ++r)
                out[(size_t)(grow + r) * OUT_F + gcol] = facc[mi][ni][r] + bv;
        }
    }
}

// ---- fallback (small ws; never expected — ws proven ~721MB): R11-style
// direct-Q kernel (BM=128, BN=64, BK=128, grid 688), Q int32 reg-staged.
__global__ __launch_bounds__(256) void qgemm10_fb(
    const char*  __restrict__ Xq,
    const float* __restrict__ xsc,
    const float* __restrict__ X,
    const int*   __restrict__ Q,
    const float* __restrict__ scale,
    const float* __restrict__ bias,
    const int*   __restrict__ tabi,
    const float* __restrict__ tabf,
    float* __restrict__ out)
{
    __shared__ char sA[2][BM * BK];
    __shared__ char sB[2][BN * BK];
    __shared__ int   list[256];
    __shared__ float ldel[256];
    __shared__ int   lcount;

    const int tid  = threadIdx.x;
    const int wave = tid >> 6;
    const int lane = tid & 63;

    const int lin = blockIdx.x;
    const int t0  = (lin & 7) * (NWG / 8) + (lin >> 3);
    const int col0 = (t0 >> 2) * BN;
    const int row0 = (t0 & 3) * BM;

    const int wm = (wave >> 1) * 64;
    const int wn = (wave & 1) * 32;
    const int fr = lane & 15;
    const int fc = lane >> 4;

    int4v acc[4][2] = {};

    const char* asrc =
        Xq + (size_t)(row0 + wave * 32 + (lane >> 3)) * IN_F
           + (((lane & 7) ^ (lane >> 3)) * 16);
    auto issueA = [&](int buf, int k0) {
        #pragma unroll
        for (int i = 0; i < 4; ++i)
            __builtin_amdgcn_global_load_lds(
                (const __attribute__((address_space(1))) void*)(asrc + (size_t)i * 8 * IN_F + k0),
                (__attribute__((address_space(3))) void*)&sA[buf][(wave * 32 + i * 8) * BK],
                16, 0, 0);
    };

    const int srb = tid >> 2;
    const int* bsrc = Q + (size_t)(col0 + srb) * IN_F + (tid & 3) * 32;
    int4v br0, br1, br2, br3, br4, br5, br6, br7;
    auto loadB = [&](int k0) {
        br0 = *(const int4v*)(bsrc + k0 + 0);
        br1 = *(const int4v*)(bsrc + k0 + 4);
        br2 = *(const int4v*)(bsrc + k0 + 8);
        br3 = *(const int4v*)(bsrc + k0 + 12);
        br4 = *(const int4v*)(bsrc + k0 + 16);
        br5 = *(const int4v*)(bsrc + k0 + 20);
        br6 = *(const int4v*)(bsrc + k0 + 24);
        br7 = *(const int4v*)(bsrc + k0 + 28);
    };
    auto writeB = [&](int buf) {
        int4v w0, w1;
        w0[0] = pack4(br0[0], br0[1], br0[2], br0[3]);
        w0[1] = pack4(br1[0], br1[1], br1[2], br1[3]);
        w0[2] = pack4(br2[0], br2[1], br2[2], br2[3]);
        w0[3] = pack4(br3[0], br3[1], br3[2], br3[3]);
        w1[0] = pack4(br4[0], br4[1], br4[2], br4[3]);
        w1[1] = pack4(br5[0], br5[1], br5[2], br5[3]);
        w1[2] = pack4(br6[0], br6[1], br6[2], br6[3]);
        w1[3] = pack4(br7[0], br7[1], br7[2], br7[3]);
        const int c0 = (tid & 3) * 2;
        const int s7 = srb & 7;
        *(int4v*)&sB[buf][srb * BK + ((c0 ^ s7) * 16)]       = w0;
        *(int4v*)&sB[buf][srb * BK + (((c0 + 1) ^ s7) * 16)] = w1;
    };

    loadB(0);
    issueA(0, 0);
    writeB(0);
    loadB(BK);
    asm volatile("s_waitcnt vmcnt(8) lgkmcnt(0)" ::: "memory");
    __builtin_amdgcn_s_barrier();

    for (int t = 0; t < NT; ++t) {
        const int cur = t & 1;
        if (t + 1 < NT) issueA(cur ^ 1, (t + 1) * BK);

        __builtin_amdgcn_s_setprio(1);
        #pragma unroll
        for (int kk = 0; kk < 2; ++kk) {
            int4v fa[4], fb[2];
            #pragma unroll
            for (int mi = 0; mi < 4; ++mi) {
                const int row = wm + mi * 16 + fr;
                fa[mi] = *(const int4v*)&sA[cur][row * BK + (((kk * 4 + fc) ^ (row & 7)) * 16)];
            }
            #pragma unroll
            for (int ni = 0; ni < 2; ++ni) {
                const int row = wn + ni * 16 + fr;
                fb[ni] = *(const int4v*)&sB[cur][row * BK + (((kk * 4 + fc) ^ (row & 7)) * 16)];
            }
            #pragma unroll
            for (int mi = 0; mi < 4; ++mi)
                #pragma unroll
                for (int ni = 0; ni < 2; ++ni)
                    acc[mi][ni] = __builtin_amdgcn_mfma_i32_16x16x64_i8(
                        fa[mi], fb[ni], acc[mi][ni], 0, 0, 0);
        }
        __builtin_amdgcn_s_setprio(0);

        if (t + 1 < NT) writeB(cur ^ 1);
        if (t + 2 < NT) loadB((t + 2) * BK);

        if (t + 2 < NT)
            asm volatile("s_waitcnt vmcnt(8) lgkmcnt(0)" ::: "memory");
        else
            asm volatile("s_waitcnt vmcnt(0) lgkmcnt(0)" ::: "memory");
        __builtin_amdgcn_s_barrier();
    }

    const int ec = fr;
    const int er = fc * 4;
    float xs_[4][4];
    #pragma unroll
    for (int mi = 0; mi < 4; ++mi)
        #pragma unroll
        for (int r = 0; r < 4; ++r)
            xs_[mi][r] = xsc[row0 + wm + mi * 16 + er + r];

    f32x4 facc[4][2];
    #pragma unroll
    for (int ni = 0; ni < 2; ++ni) {
        const float qsc = scale[col0 + wn + ni * 16 + ec];
        #pragma unroll
        for (int mi = 0; mi < 4; ++mi)
            #pragma unroll
            for (int r = 0; r < 4; ++r)
                facc[mi][ni][r] = (float)acc[mi][ni][r] * qsc * xs_[mi][r];
    }

    if (tid == 0) lcount = 0;
    __syncthreads();
    for (int c = tid; c < NOUT; c += 256) {
        const int p = tabi[c];
        const int r = p >> 16;
        if (r >= col0 && r < col0 + BN) {
            const int pos = atomicAdd(&lcount, 1);
            if (pos < 256) { list[pos] = p; ldel[pos] = tabf[c]; }
        }
    }
    __syncthreads();
    const int nm = lcount < 256 ? lcount : 256;
    for (int u = 0; u < nm; ++u) {
        const int p    = list[u];
        const int ocl  = (p >> 16) - col0;
        const int ocol = p & 0xFFFF;
        if (((ocl >> 5) == (wave & 1)) && ((lane & 15) == (ocl & 15))) {
            const float d = ldel[u];
            #pragma unroll
            for (int nn = 0; nn < 2; ++nn) {
                if (nn == ((ocl >> 4) & 1)) {
                    #pragma unroll
                    for (int mi = 0; mi < 4; ++mi)
                        #pragma unroll
                        for (int r2 = 0; r2 < 4; ++r2) {
                            const int grow = row0 + wm + mi * 16 + er + r2;
                            facc[mi][nn][r2] += d * X[(size_t)grow * IN_F + ocol];
                        }
                }
            }
        }
    }

    #pragma unroll
    for (int ni = 0; ni < 2; ++ni) {
        const int gcol = col0 + wn + ni * 16 + ec;
        const float bv = bias[gcol];
        #pragma unroll
        for (int mi = 0; mi < 4; ++mi) {
            const int grow = row0 + wm + mi * 16 + er;
            #pragma unroll
            for (int r = 0; r < 4; ++r)
                out[(size_t)(grow + r) * OUT_F + gcol] = facc[mi][ni][r] + bv;
        }
    }
}

extern "C" void kernel_launch(void* const* d_in, const int* in_sizes, int n_in,
                              void* d_out, int out_size, void* d_ws, size_t ws_size,
                              hipStream_t stream) {
    const float* x    = (const float*)d_in[0];
    const int*   q    = (const int*)d_in[1];
    const float* qs   = (const float*)d_in[2];
    const float* qo   = (const float*)d_in[3];
    const int*   qi   = (const int*)d_in[4];
    const float* bias = (const float*)d_in[5];
    float* out = (float*)d_out;

    char*  Xq   = (char*)d_ws;
    float* xsc  = (float*)((char*)d_ws + WS_XSC);
    int*   tabi = (int*)((char*)d_ws + WS_TAB_I);
    float* tabf = (float*)((char*)d_ws + WS_TAB_F);
    int*   hkey = (int*)((char*)d_ws + WS_HKEY);
    int*   hval = (int*)((char*)d_ws + WS_HVAL);
    char*  Qb8  = (char*)d_ws + WS_QB8;

    prep_xq<<<dim3(SEQ), 256, 0, stream>>>(x, Xq, xsc);
    hipMemsetAsync((void*)hkey, 0xFF, (size_t)HSLOTS * 8, stream);  // hkey+hval = -1
    prep_hins<<<dim3(NOUT / 256), 256, 0, stream>>>(qi, hkey, hval);
    prep_tab<<<dim3(NOUT / 256), 256, 0, stream>>>(qi, qo, q, qs, hkey, hval, tabi, tabf);

    if (ws_size >= WS_NEED) {
        prep_q8<<<dim3((OUT_F * IN_F) / 4096), 256, 0, stream>>>(q, Qb8);
        qgemm15<<<dim3(NWG), 512, 0, stream>>>(Xq, xsc, x, Qb8, qs, bias, tabi, tabf, out);
    } else {
        qgemm10_fb<<<dim3(NWG), 256, 0, stream>>>(Xq, xsc, x, q, qs, bias, tabi, tabf, out);
    }
}